// Round 2
// baseline (1077.167 us; speedup 1.0000x reference)
//
#include <hip/hip_runtime.h>
#include <hip/hip_bf16.h>
#include <hip/hip_fp16.h>

#define D 128
#define BM 128
#define BN 128
#define LDK 72  // padded LDS k-stride (bf16 elems): 144B rows -> 2-way bank aliasing only (free)

typedef __attribute__((ext_vector_type(8))) __bf16 bf16x8;
typedef __attribute__((ext_vector_type(4))) float f32x4;
typedef __hip_bfloat16 bf16;

__device__ __forceinline__ float bf2f(bf16 v) { return __bfloat162float(v); }
__device__ __forceinline__ bf16 f2bf(float v) { return __float2bfloat16(v); }

// ---------------- dtype probe: are the float tensors bf16 or fp32? ----------------
// Read Wl as bf16. True bf16 weights (sigma=0.05): |v| <= ~0.35, zero implausibles.
// fp32 bits read as bf16 pairs: mantissa halves are random 16-bit patterns, ~25%
// decode to |v|>4 / Inf / NaN. flag=1 -> inputs are fp32.
__global__ void probe_kernel(const unsigned short* __restrict__ w, int n, int* __restrict__ flag) {
  __shared__ int cnt[256];
  int t = threadIdx.x;
  int bad = 0;
  int lim = n < 65536 ? n : 65536;
  for (int i = t; i < lim; i += 256) {
    unsigned int u = ((unsigned int)w[i]) << 16;
    float v = __uint_as_float(u);
    if (!(fabsf(v) <= 4.0f)) bad++;  // catches NaN too
  }
  cnt[t] = bad;
  __syncthreads();
  for (int off = 128; off > 0; off >>= 1) {
    if (t < off) cnt[t] += cnt[t + off];
    __syncthreads();
  }
  if (t == 0) flag[0] = (cnt[0] > 2048) ? 1 : 0;
}

// fp32 mode only: materialize canonical bf16 copies of x and h.
__global__ void convert_kernel(const float* __restrict__ xf, const float* __restrict__ hf,
                               bf16* __restrict__ xb, bf16* __restrict__ hb,
                               const int* __restrict__ flag, int nx, int nh) {
  if (flag[0] == 0) return;
  int i = blockIdx.x * blockDim.x + threadIdx.x;
  if (i < nx) xb[i] = f2bf(xf[i]);
  if (i < nh) hb[i] = f2bf(hf[i]);
}

// ---------------- graph preprocessing ----------------

__global__ void zero_int_kernel(int* p, int n) {
  int i = blockIdx.x * blockDim.x + threadIdx.x;
  if (i < n) p[i] = 0;
}

__global__ void count_deg_kernel(const int* __restrict__ dst, int* __restrict__ deg, int E) {
  int e = blockIdx.x * blockDim.x + threadIdx.x;
  if (e < E) atomicAdd(&deg[dst[e]], 1);
}

__global__ void scan_kernel(const int* __restrict__ deg, int* __restrict__ offs,
                            int* __restrict__ cursor, float* __restrict__ inv_deg, int N) {
  __shared__ int sums[1024];
  int t = threadIdx.x;
  int chunk = (N + 1023) >> 10;
  int lo = t * chunk;
  int hi = lo + chunk;
  if (lo > N) lo = N;
  if (hi > N) hi = N;
  int s = 0;
  for (int i = lo; i < hi; ++i) s += deg[i];
  sums[t] = s;
  __syncthreads();
  for (int off = 1; off < 1024; off <<= 1) {
    int v = sums[t];
    int add = (t >= off) ? sums[t - off] : 0;
    __syncthreads();
    sums[t] = v + add;
    __syncthreads();
  }
  int run = (t == 0) ? 0 : sums[t - 1];
  for (int i = lo; i < hi; ++i) {
    offs[i] = run;
    cursor[i] = run;
    int d = deg[i];
    inv_deg[i] = 1.0f / (float)(d > 1 ? d : 1);
    run += d;
  }
  if (t == 1023) offs[N] = sums[1023];
}

__global__ void scatter_kernel(const int* __restrict__ src, const int* __restrict__ dst,
                               int* __restrict__ cursor, int* __restrict__ esrc, int E) {
  int e = blockIdx.x * blockDim.x + threadIdx.x;
  if (e < E) {
    int pos = atomicAdd(&cursor[dst[e]], 1);
    esrc[pos] = src[e];
  }
}

// ---------------- mean aggregation (CSR gather, one wave per node) ----------------

__global__ void agg_kernel(const bf16* __restrict__ featA, const bf16* __restrict__ featB,
                           const int* __restrict__ flag, const int* __restrict__ esrc,
                           const int* __restrict__ offs, const float* __restrict__ inv_deg,
                           bf16* __restrict__ out, int N) {
  const bf16* feat = flag[0] ? featB : featA;
  int node = (int)((blockIdx.x * (size_t)blockDim.x + threadIdx.x) >> 6);
  int lane = threadIdx.x & 63;
  if (node >= N) return;
  int e0 = offs[node], e1 = offs[node + 1];
  float a0 = 0.f, a1 = 0.f;
  int c = lane * 2;
  for (int e = e0; e < e1; ++e) {
    int s = esrc[e];
    __hip_bfloat162 v = *(const __hip_bfloat162*)(feat + (size_t)s * D + c);
    a0 += bf2f(v.x);
    a1 += bf2f(v.y);
  }
  float w = inv_deg[node];
  __hip_bfloat162 o;
  o.x = f2bf(a0 * w);
  o.y = f2bf(a1 * w);
  *(__hip_bfloat162*)(out + (size_t)node * D + c) = o;
}

// ---------------- weight packing: B^T layout [n][k], k = 4 blocks of 128 ----------------

__device__ __forceinline__ float loadw(const void* p, size_t idx, int fl) {
  return fl ? ((const float*)p)[idx] : bf2f(((const bf16*)p)[idx]);
}

__global__ void pack_kernel(const void* __restrict__ Wl, const void* __restrict__ Wr,
                            const void* __restrict__ b, int l, const int* __restrict__ flag,
                            bf16* __restrict__ B1p, bf16* __restrict__ B2p,
                            float* __restrict__ bs1, float* __restrict__ bs2) {
  int fl = flag[0];
  int idx = blockIdx.x * blockDim.x + threadIdx.x;
  const int SZ1 = 256 * 512;
  const int SZ2 = 128 * 512;
  if (idx < SZ1) {
    int n = idx >> 9, k = idx & 511;
    int p = k >> 7, kr = k & 127;
    int gpair = n >> 7, nc = n & 127;
    int gate = gpair * 2 + (p >> 1);
    const void* W = (p & 1) ? Wr : Wl;
    B1p[idx] = f2bf(loadw(W, (((size_t)l * 6 + gate) * D + kr) * D + nc, fl));
  } else if (idx < SZ1 + SZ2) {
    int i2 = idx - SZ1;
    int n = i2 >> 9, k = i2 & 511;
    int p = k >> 7, kr = k & 127;
    int gate = 4 + (p >> 1);
    const void* W = (p & 1) ? Wr : Wl;
    B2p[i2] = f2bf(loadw(W, (((size_t)l * 6 + gate) * D + kr) * D + n, fl));
  } else if (idx < SZ1 + SZ2 + 384) {
    int c = idx - (SZ1 + SZ2);
    if (c < 256) {
      int g0 = (c >> 7) * 2;
      int cc = c & 127;
      bs1[c] = loadw(b, ((size_t)l * 6 + g0) * D + cc, fl) +
               loadw(b, ((size_t)l * 6 + g0 + 1) * D + cc, fl);
    } else {
      int cc = c - 256;
      bs2[cc] = loadw(b, ((size_t)l * 6 + 4) * D + cc, fl) +
                loadw(b, ((size_t)l * 6 + 5) * D + cc, fl);
    }
  }
}

// ---------------- MFMA GEMM mainloop: C[128x128] = A[128x512] @ B[512x128] ----------------
// A given as 4 row-major [M,128] bf16 blocks; Bp row-major [NCOLS,512] (i.e. B^T).

__device__ __forceinline__ void gemm_mainloop(const bf16* A0, const bf16* A1, const bf16* A2,
                                              const bf16* A3, const bf16* __restrict__ Bp, int M,
                                              int row0, int col0, bf16* As, bf16* Bs,
                                              f32x4 (&acc)[4][4]) {
  int tid = threadIdx.x;
  int wave = tid >> 6, lane = tid & 63;
  int wrow = (wave >> 1) * 64, wcol = (wave & 1) * 64;
  const bf16* Ablk[4] = {A0, A1, A2, A3};
#pragma unroll
  for (int kt = 0; kt < 8; ++kt) {
    const int kglob = kt * 64;
    const bf16* Aptr = Ablk[kglob >> 7];
    const int kr = kglob & 127;
#pragma unroll
    for (int i = 0; i < 4; ++i) {
      int c = tid + i * 256;
      int r = c >> 3;
      int ko = (c & 7) * 8;
      int rg = row0 + r;
      if (rg > M - 1) rg = M - 1;  // clamp: garbage rows never stored
      uint4 va = *(const uint4*)(const void*)(Aptr + (size_t)rg * D + kr + ko);
      *(uint4*)(void*)(As + r * LDK + ko) = va;
      uint4 vb = *(const uint4*)(const void*)(Bp + (size_t)(col0 + r) * 512 + kglob + ko);
      *(uint4*)(void*)(Bs + r * LDK + ko) = vb;
    }
    __syncthreads();
#pragma unroll
    for (int kk = 0; kk < 2; ++kk) {
      int kb = kk * 32 + (lane >> 4) * 8;
      int mr = lane & 15;
      bf16x8 af[4], bfv[4];
#pragma unroll
      for (int mi = 0; mi < 4; ++mi)
        af[mi] = *(const bf16x8*)(const void*)(As + (wrow + mi * 16 + mr) * LDK + kb);
#pragma unroll
      for (int ni = 0; ni < 4; ++ni)
        bfv[ni] = *(const bf16x8*)(const void*)(Bs + (wcol + ni * 16 + mr) * LDK + kb);
#pragma unroll
      for (int mi = 0; mi < 4; ++mi)
#pragma unroll
        for (int ni = 0; ni < 4; ++ni)
          acc[mi][ni] =
              __builtin_amdgcn_mfma_f32_16x16x32_bf16(af[mi], bfv[ni], acc[mi][ni], 0, 0, 0);
    }
    __syncthreads();
  }
}

// GEMM1: cols 0..127 -> z = sigmoid(.) (fp16); cols 128..255 -> rh = sigmoid(.)*h (bf16)
__global__ __launch_bounds__(256) void gemm1_kernel(
    const bf16* A0, const bf16* A1a, const bf16* A1b, const bf16* A2, const bf16* A3a,
    const bf16* A3b, const int* __restrict__ flag, const bf16* __restrict__ Bp,
    const float* __restrict__ bias, __half* __restrict__ z, bf16* __restrict__ rh, int M) {
  int fl = flag[0];
  const bf16* A1 = fl ? A1b : A1a;
  const bf16* A3 = fl ? A3b : A3a;
  const bf16* hl = A3;
  __shared__ bf16 As[BM * LDK];
  __shared__ bf16 Bs[BN * LDK];
  f32x4 acc[4][4];
#pragma unroll
  for (int i = 0; i < 4; ++i)
#pragma unroll
    for (int j = 0; j < 4; ++j) acc[i][j] = (f32x4){0.f, 0.f, 0.f, 0.f};
  int row0 = blockIdx.x * BM, col0 = blockIdx.y * BN;
  gemm_mainloop(A0, A1, A2, A3, Bp, M, row0, col0, As, Bs, acc);
  int lane = threadIdx.x & 63, wave = threadIdx.x >> 6;
  int wrow = (wave >> 1) * 64, wcol = (wave & 1) * 64;
  int mr = lane & 15, quad = lane >> 4;
#pragma unroll
  for (int mi = 0; mi < 4; ++mi)
#pragma unroll
    for (int ni = 0; ni < 4; ++ni)
#pragma unroll
      for (int r = 0; r < 4; ++r) {
        int grow = row0 + wrow + mi * 16 + quad * 4 + r;
        if (grow >= M) continue;
        int gcol = col0 + wcol + ni * 16 + mr;
        float v = acc[mi][ni][r] + bias[gcol];
        float sg = 1.0f / (1.0f + __expf(-v));
        if (gcol < 128) {
          z[(size_t)grow * D + gcol] = __float2half(sg);
        } else {
          int cc = gcol - 128;
          float hv = bf2f(hl[(size_t)grow * D + cc]);
          rh[(size_t)grow * D + cc] = f2bf(sg * hv);
        }
      }
}

// GEMM2: out = z*h + (1-z)*tanh(pre); out dtype per flag; bf16 shadow into nextb (fp32 mode)
__global__ __launch_bounds__(256) void gemm2_kernel(
    const bf16* A0, const bf16* A1a, const bf16* A1b, const bf16* A2, const bf16* A3,
    const bf16* A3hA, const bf16* A3hB, const int* __restrict__ flag, const bf16* __restrict__ Bp,
    const float* __restrict__ bias, const __half* __restrict__ z, void* __restrict__ outbase,
    size_t lND, bf16* __restrict__ nextb, int M) {
  int fl = flag[0];
  const bf16* A1 = fl ? A1b : A1a;
  const bf16* hl = fl ? A3hB : A3hA;
  __shared__ bf16 As[BM * LDK];
  __shared__ bf16 Bs[BN * LDK];
  f32x4 acc[4][4];
#pragma unroll
  for (int i = 0; i < 4; ++i)
#pragma unroll
    for (int j = 0; j < 4; ++j) acc[i][j] = (f32x4){0.f, 0.f, 0.f, 0.f};
  int row0 = blockIdx.x * BM, col0 = 0;
  gemm_mainloop(A0, A1, A2, A3, Bp, M, row0, col0, As, Bs, acc);
  int lane = threadIdx.x & 63, wave = threadIdx.x >> 6;
  int wrow = (wave >> 1) * 64, wcol = (wave & 1) * 64;
  int mr = lane & 15, quad = lane >> 4;
#pragma unroll
  for (int mi = 0; mi < 4; ++mi)
#pragma unroll
    for (int ni = 0; ni < 4; ++ni)
#pragma unroll
      for (int r = 0; r < 4; ++r) {
        int grow = row0 + wrow + mi * 16 + quad * 4 + r;
        if (grow >= M) continue;
        int gcol = col0 + wcol + ni * 16 + mr;
        float pre = acc[mi][ni][r] + bias[gcol];
        float ht = tanhf(pre);
        size_t off = (size_t)grow * D + gcol;
        float zv = __half2float(z[off]);
        float hv = bf2f(hl[off]);
        float ov = zv * hv + (1.0f - zv) * ht;
        if (fl) {
          ((float*)outbase)[lND + off] = ov;
          nextb[off] = f2bf(ov);
        } else {
          ((bf16*)outbase)[lND + off] = f2bf(ov);
        }
      }
}

// ---------------- launch ----------------

extern "C" void kernel_launch(void* const* d_in, const int* in_sizes, int n_in, void* d_out,
                              int out_size, void* d_ws, size_t ws_size, hipStream_t stream) {
  const void* x = d_in[0];
  const void* h = d_in[1];
  const void* Wl = d_in[2];
  const void* Wr = d_in[3];
  const void* b = d_in[4];
  const int* src = (const int*)d_in[5];
  const int* dst = (const int*)d_in[6];

  const int NX = in_sizes[0];
  const int NH = in_sizes[1];
  const int N = NX / D;
  const int E = in_sizes[5];
  const int L = NH / NX;
  (void)n_in;
  (void)out_size;
  (void)ws_size;

  char* ws = (char*)d_ws;
  size_t off = 0;
  auto alloc = [&](size_t bytes) -> char* {
    char* p = ws + off;
    off = (off + bytes + 255) & ~(size_t)255;
    return p;
  };
  // bf16-mode footprint first (~55 MB); fp32-only buffers last.
  int* flag = (int*)alloc(256);
  int* deg = (int*)alloc((size_t)N * 4);
  int* offs = (int*)alloc((size_t)(N + 1) * 4);
  int* cursor = (int*)alloc((size_t)N * 4);
  float* inv_deg = (float*)alloc((size_t)N * 4);
  int* esrc = (int*)alloc((size_t)E * 4);
  bf16* agg_inp = (bf16*)alloc((size_t)N * D * 2);
  bf16* agg2 = (bf16*)alloc((size_t)N * D * 2);
  bf16* rh = (bf16*)alloc((size_t)N * D * 2);
  __half* z = (__half*)alloc((size_t)N * D * 2);
  bf16* B1p = (bf16*)alloc(256 * 512 * 2);
  bf16* B2p = (bf16*)alloc(128 * 512 * 2);
  float* bs1 = (float*)alloc(256 * 4);
  float* bs2 = (float*)alloc(128 * 4);
  bf16* xb = (bf16*)alloc((size_t)NX * 2);  // fp32 mode only
  bf16* hb = (bf16*)alloc((size_t)NH * 2);  // fp32 mode only

  probe_kernel<<<1, 256, 0, stream>>>((const unsigned short*)Wl, in_sizes[2], flag);
  int ncv = NX > NH ? NX : NH;
  convert_kernel<<<(ncv + 255) / 256, 256, 0, stream>>>((const float*)x, (const float*)h, xb, hb,
                                                        flag, NX, NH);

  zero_int_kernel<<<(N + 255) / 256, 256, 0, stream>>>(deg, N);
  count_deg_kernel<<<(E + 255) / 256, 256, 0, stream>>>(dst, deg, E);
  scan_kernel<<<1, 1024, 0, stream>>>(deg, offs, cursor, inv_deg, N);
  scatter_kernel<<<(E + 255) / 256, 256, 0, stream>>>(src, dst, cursor, esrc, E);

  int mtiles = (N + BM - 1) / BM;
  const int pack_elems = 256 * 512 + 128 * 512 + 384;
  for (int l = 0; l < L; ++l) {
    const size_t lND = (size_t)l * N * D;
    // bf16-mode input pointer; fp32-mode input is always xb (x converted, or out[l-1] shadow)
    const bf16* inpA = (l == 0) ? (const bf16*)x : ((const bf16*)d_out + lND - (size_t)N * D);
    const bf16* hlA = (const bf16*)h + lND;
    const bf16* hlB = hb + lND;

    pack_kernel<<<(pack_elems + 255) / 256, 256, 0, stream>>>(Wl, Wr, b, l, flag, B1p, B2p, bs1,
                                                              bs2);
    agg_kernel<<<(N + 3) / 4, 256, 0, stream>>>(inpA, xb, flag, esrc, offs, inv_deg, agg_inp, N);
    agg_kernel<<<(N + 3) / 4, 256, 0, stream>>>(hlA, hlB, flag, esrc, offs, inv_deg, agg2, N);
    gemm1_kernel<<<dim3(mtiles, 2), 256, 0, stream>>>(agg_inp, inpA, xb, agg2, hlA, hlB, flag, B1p,
                                                      bs1, z, rh, N);
    agg_kernel<<<(N + 3) / 4, 256, 0, stream>>>(rh, rh, flag, esrc, offs, inv_deg, agg2, N);
    gemm2_kernel<<<dim3(mtiles, 1), 256, 0, stream>>>(agg_inp, inpA, xb, agg2, rh, hlA, hlB, flag,
                                                      B2p, bs2, z, d_out, lND, xb, N);
  }
}

// Round 3
// 831.247 us; speedup vs baseline: 1.2958x; 1.2958x over previous
//
#include <hip/hip_runtime.h>
#include <hip/hip_bf16.h>
#include <hip/hip_fp16.h>

#define D 128
#define BM 128
#define BN 128
#define LDK 72  // padded LDS k-stride (bf16 elems): 144B rows -> 2-way bank aliasing only (free)
#define SCAN_BLK 1024  // elements per scan block (256 thr x 4)

typedef __attribute__((ext_vector_type(8))) __bf16 bf16x8;
typedef __attribute__((ext_vector_type(4))) float f32x4;
typedef __hip_bfloat16 bf16;

__device__ __forceinline__ float bf2f(bf16 v) { return __bfloat162float(v); }
__device__ __forceinline__ bf16 f2bf(float v) { return __float2bfloat16(v); }

// ---------------- dtype probe: are the float tensors bf16 or fp32? ----------------
__global__ void probe_kernel(const unsigned short* __restrict__ w, int n, int* __restrict__ flag) {
  __shared__ int cnt[256];
  int t = threadIdx.x;
  int bad = 0;
  int lim = n < 65536 ? n : 65536;
  for (int i = t; i < lim; i += 256) {
    unsigned int u = ((unsigned int)w[i]) << 16;
    float v = __uint_as_float(u);
    if (!(fabsf(v) <= 4.0f)) bad++;  // catches NaN too
  }
  cnt[t] = bad;
  __syncthreads();
  for (int off = 128; off > 0; off >>= 1) {
    if (t < off) cnt[t] += cnt[t + off];
    __syncthreads();
  }
  if (t == 0) flag[0] = (cnt[0] > 2048) ? 1 : 0;
}

// fp32 mode only: materialize canonical bf16 copies of x and h.
__global__ void convert_kernel(const float* __restrict__ xf, const float* __restrict__ hf,
                               bf16* __restrict__ xb, bf16* __restrict__ hb,
                               const int* __restrict__ flag, int nx, int nh) {
  if (flag[0] == 0) return;
  int i = blockIdx.x * blockDim.x + threadIdx.x;
  if (i < nx) xb[i] = f2bf(xf[i]);
  if (i < nh) hb[i] = f2bf(hf[i]);
}

// ---------------- graph preprocessing ----------------

__global__ void zero_int_kernel(int* p, int n) {
  int i = blockIdx.x * blockDim.x + threadIdx.x;
  if (i < n) p[i] = 0;
}

__global__ void count_deg_kernel(const int* __restrict__ dst, int* __restrict__ deg, int E) {
  int e = blockIdx.x * blockDim.x + threadIdx.x;
  if (e < E) atomicAdd(&deg[dst[e]], 1);
}

// phase 1: per-block sums of 1024 deg values
__global__ void scan1_kernel(const int* __restrict__ deg, int* __restrict__ bsum, int N) {
  __shared__ int lsum[256];
  int t = threadIdx.x;
  int base = blockIdx.x * SCAN_BLK + t * 4;
  int s = 0;
  if (base + 3 < N) {
    int4 v = *(const int4*)(deg + base);
    s = v.x + v.y + v.z + v.w;
  } else {
    for (int i = 0; i < 4; ++i)
      if (base + i < N) s += deg[base + i];
  }
  lsum[t] = s;
  __syncthreads();
  for (int off = 128; off > 0; off >>= 1) {
    if (t < off) lsum[t] += lsum[t + off];
    __syncthreads();
  }
  if (t == 0) bsum[blockIdx.x] = lsum[0];
}

// phase 2: exclusive scan of block sums (nb <= 256), single block
__global__ void scan2_kernel(int* __restrict__ bsum, int nb) {
  __shared__ int sh[256];
  int t = threadIdx.x;
  sh[t] = (t < nb) ? bsum[t] : 0;
  __syncthreads();
  for (int off = 1; off < 256; off <<= 1) {
    int v = sh[t];
    int add = (t >= off) ? sh[t - off] : 0;
    __syncthreads();
    sh[t] = v + add;
    __syncthreads();
  }
  if (t < nb) bsum[t] = (t == 0) ? 0 : sh[t - 1];
}

// phase 3: per-block local scan + block offset -> offs/cursor/inv_deg
__global__ void scan3_kernel(const int* __restrict__ deg, const int* __restrict__ bsum,
                             int* __restrict__ offs, int* __restrict__ cursor,
                             float* __restrict__ inv_deg, int N, int E) {
  __shared__ int lsum[256];
  int t = threadIdx.x;
  int base = blockIdx.x * SCAN_BLK + t * 4;
  int d0 = 0, d1 = 0, d2 = 0, d3 = 0;
  if (base + 3 < N) {
    int4 v = *(const int4*)(deg + base);
    d0 = v.x; d1 = v.y; d2 = v.z; d3 = v.w;
  } else {
    if (base + 0 < N) d0 = deg[base + 0];
    if (base + 1 < N) d1 = deg[base + 1];
    if (base + 2 < N) d2 = deg[base + 2];
    if (base + 3 < N) d3 = deg[base + 3];
  }
  lsum[t] = d0 + d1 + d2 + d3;
  __syncthreads();
  for (int off = 1; off < 256; off <<= 1) {
    int v = lsum[t];
    int add = (t >= off) ? lsum[t - off] : 0;
    __syncthreads();
    lsum[t] = v + add;
    __syncthreads();
  }
  int run = bsum[blockIdx.x] + ((t == 0) ? 0 : lsum[t - 1]);
  int dd[4] = {d0, d1, d2, d3};
  for (int i = 0; i < 4; ++i) {
    int idx = base + i;
    if (idx < N) {
      offs[idx] = run;
      cursor[idx] = run;
      inv_deg[idx] = 1.0f / (float)(dd[i] > 1 ? dd[i] : 1);
      run += dd[i];
    }
  }
  if (blockIdx.x == 0 && t == 0) offs[N] = E;
}

__global__ void scatter_kernel(const int* __restrict__ src, const int* __restrict__ dst,
                               int* __restrict__ cursor, int* __restrict__ esrc, int E) {
  int e = blockIdx.x * blockDim.x + threadIdx.x;
  if (e < E) {
    int pos = atomicAdd(&cursor[dst[e]], 1);
    esrc[pos] = src[e];
  }
}

// ---------------- mean aggregation (CSR gather, one wave per node) ----------------

__global__ void agg_kernel(const bf16* __restrict__ featA, const bf16* __restrict__ featB,
                           const int* __restrict__ flag, const int* __restrict__ esrc,
                           const int* __restrict__ offs, const float* __restrict__ inv_deg,
                           bf16* __restrict__ out, int N) {
  const bf16* feat = flag[0] ? featB : featA;
  int node = (int)((blockIdx.x * (size_t)blockDim.x + threadIdx.x) >> 6);
  int lane = threadIdx.x & 63;
  if (node >= N) return;
  int e0 = offs[node], e1 = offs[node + 1];
  float a0 = 0.f, a1 = 0.f;
  int c = lane * 2;
  for (int e = e0; e < e1; ++e) {
    int s = esrc[e];
    __hip_bfloat162 v = *(const __hip_bfloat162*)(feat + (size_t)s * D + c);
    a0 += bf2f(v.x);
    a1 += bf2f(v.y);
  }
  float w = inv_deg[node];
  __hip_bfloat162 o;
  o.x = f2bf(a0 * w);
  o.y = f2bf(a1 * w);
  *(__hip_bfloat162*)(out + (size_t)node * D + c) = o;
}

// dual gather: aggregate two feature matrices over the same edge walk
__global__ void agg_dual_kernel(const bf16* __restrict__ fAa, const bf16* __restrict__ fAb,
                                const bf16* __restrict__ fBa, const bf16* __restrict__ fBb,
                                const int* __restrict__ flag, const int* __restrict__ esrc,
                                const int* __restrict__ offs, const float* __restrict__ inv_deg,
                                bf16* __restrict__ outA, bf16* __restrict__ outB, int N) {
  int fl = flag[0];
  const bf16* fA = fl ? fAb : fAa;
  const bf16* fB = fl ? fBb : fBa;
  int node = (int)((blockIdx.x * (size_t)blockDim.x + threadIdx.x) >> 6);
  int lane = threadIdx.x & 63;
  if (node >= N) return;
  int e0 = offs[node], e1 = offs[node + 1];
  float a0 = 0.f, a1 = 0.f, b0 = 0.f, b1 = 0.f;
  int c = lane * 2;
  for (int e = e0; e < e1; ++e) {
    int s = esrc[e];
    size_t ro = (size_t)s * D + c;
    __hip_bfloat162 va = *(const __hip_bfloat162*)(fA + ro);
    __hip_bfloat162 vb = *(const __hip_bfloat162*)(fB + ro);
    a0 += bf2f(va.x);
    a1 += bf2f(va.y);
    b0 += bf2f(vb.x);
    b1 += bf2f(vb.y);
  }
  float w = inv_deg[node];
  __hip_bfloat162 oa, ob;
  oa.x = f2bf(a0 * w);
  oa.y = f2bf(a1 * w);
  ob.x = f2bf(b0 * w);
  ob.y = f2bf(b1 * w);
  *(__hip_bfloat162*)(outA + (size_t)node * D + c) = oa;
  *(__hip_bfloat162*)(outB + (size_t)node * D + c) = ob;
}

// ---------------- weight packing: B^T layout [n][k], k = 4 blocks of 128 ----------------

__device__ __forceinline__ float loadw(const void* p, size_t idx, int fl) {
  return fl ? ((const float*)p)[idx] : bf2f(((const bf16*)p)[idx]);
}

__global__ void pack_kernel(const void* __restrict__ Wl, const void* __restrict__ Wr,
                            const void* __restrict__ b, int l, const int* __restrict__ flag,
                            bf16* __restrict__ B1p, bf16* __restrict__ B2p,
                            float* __restrict__ bs1, float* __restrict__ bs2) {
  int fl = flag[0];
  int idx = blockIdx.x * blockDim.x + threadIdx.x;
  const int SZ1 = 256 * 512;
  const int SZ2 = 128 * 512;
  if (idx < SZ1) {
    int n = idx >> 9, k = idx & 511;
    int p = k >> 7, kr = k & 127;
    int gpair = n >> 7, nc = n & 127;
    int gate = gpair * 2 + (p >> 1);
    const void* W = (p & 1) ? Wr : Wl;
    B1p[idx] = f2bf(loadw(W, (((size_t)l * 6 + gate) * D + kr) * D + nc, fl));
  } else if (idx < SZ1 + SZ2) {
    int i2 = idx - SZ1;
    int n = i2 >> 9, k = i2 & 511;
    int p = k >> 7, kr = k & 127;
    int gate = 4 + (p >> 1);
    const void* W = (p & 1) ? Wr : Wl;
    B2p[i2] = f2bf(loadw(W, (((size_t)l * 6 + gate) * D + kr) * D + n, fl));
  } else if (idx < SZ1 + SZ2 + 384) {
    int c = idx - (SZ1 + SZ2);
    if (c < 256) {
      int g0 = (c >> 7) * 2;
      int cc = c & 127;
      bs1[c] = loadw(b, ((size_t)l * 6 + g0) * D + cc, fl) +
               loadw(b, ((size_t)l * 6 + g0 + 1) * D + cc, fl);
    } else {
      int cc = c - 256;
      bs2[cc] = loadw(b, ((size_t)l * 6 + 4) * D + cc, fl) +
                loadw(b, ((size_t)l * 6 + 5) * D + cc, fl);
    }
  }
}

// ---------------- MFMA GEMM mainloop: C[128x128] = A[128x512] @ B[512x128] ----------------

__device__ __forceinline__ void gemm_mainloop(const bf16* A0, const bf16* A1, const bf16* A2,
                                              const bf16* A3, const bf16* __restrict__ Bp, int M,
                                              int row0, int col0, bf16* As, bf16* Bs,
                                              f32x4 (&acc)[4][4]) {
  int tid = threadIdx.x;
  int wave = tid >> 6, lane = tid & 63;
  int wrow = (wave >> 1) * 64, wcol = (wave & 1) * 64;
  const bf16* Ablk[4] = {A0, A1, A2, A3};
#pragma unroll
  for (int kt = 0; kt < 8; ++kt) {
    const int kglob = kt * 64;
    const bf16* Aptr = Ablk[kglob >> 7];
    const int kr = kglob & 127;
#pragma unroll
    for (int i = 0; i < 4; ++i) {
      int c = tid + i * 256;
      int r = c >> 3;
      int ko = (c & 7) * 8;
      int rg = row0 + r;
      if (rg > M - 1) rg = M - 1;  // clamp: garbage rows never stored
      uint4 va = *(const uint4*)(const void*)(Aptr + (size_t)rg * D + kr + ko);
      *(uint4*)(void*)(As + r * LDK + ko) = va;
      uint4 vb = *(const uint4*)(const void*)(Bp + (size_t)(col0 + r) * 512 + kglob + ko);
      *(uint4*)(void*)(Bs + r * LDK + ko) = vb;
    }
    __syncthreads();
#pragma unroll
    for (int kk = 0; kk < 2; ++kk) {
      int kb = kk * 32 + (lane >> 4) * 8;
      int mr = lane & 15;
      bf16x8 af[4], bfv[4];
#pragma unroll
      for (int mi = 0; mi < 4; ++mi)
        af[mi] = *(const bf16x8*)(const void*)(As + (wrow + mi * 16 + mr) * LDK + kb);
#pragma unroll
      for (int ni = 0; ni < 4; ++ni)
        bfv[ni] = *(const bf16x8*)(const void*)(Bs + (wcol + ni * 16 + mr) * LDK + kb);
#pragma unroll
      for (int mi = 0; mi < 4; ++mi)
#pragma unroll
        for (int ni = 0; ni < 4; ++ni)
          acc[mi][ni] =
              __builtin_amdgcn_mfma_f32_16x16x32_bf16(af[mi], bfv[ni], acc[mi][ni], 0, 0, 0);
    }
    __syncthreads();
  }
}

// GEMM1: cols 0..127 -> z = sigmoid(.) (fp16); cols 128..255 -> rh = sigmoid(.)*h (bf16)
__global__ __launch_bounds__(256) void gemm1_kernel(
    const bf16* A0, const bf16* A1a, const bf16* A1b, const bf16* A2, const bf16* A3a,
    const bf16* A3b, const int* __restrict__ flag, const bf16* __restrict__ Bp,
    const float* __restrict__ bias, __half* __restrict__ z, bf16* __restrict__ rh, int M) {
  int fl = flag[0];
  const bf16* A1 = fl ? A1b : A1a;
  const bf16* A3 = fl ? A3b : A3a;
  const bf16* hl = A3;
  __shared__ bf16 As[BM * LDK];
  __shared__ bf16 Bs[BN * LDK];
  f32x4 acc[4][4];
#pragma unroll
  for (int i = 0; i < 4; ++i)
#pragma unroll
    for (int j = 0; j < 4; ++j) acc[i][j] = (f32x4){0.f, 0.f, 0.f, 0.f};
  int row0 = blockIdx.x * BM, col0 = blockIdx.y * BN;
  gemm_mainloop(A0, A1, A2, A3, Bp, M, row0, col0, As, Bs, acc);
  int lane = threadIdx.x & 63, wave = threadIdx.x >> 6;
  int wrow = (wave >> 1) * 64, wcol = (wave & 1) * 64;
  int mr = lane & 15, quad = lane >> 4;
#pragma unroll
  for (int mi = 0; mi < 4; ++mi)
#pragma unroll
    for (int ni = 0; ni < 4; ++ni)
#pragma unroll
      for (int r = 0; r < 4; ++r) {
        int grow = row0 + wrow + mi * 16 + quad * 4 + r;
        if (grow >= M) continue;
        int gcol = col0 + wcol + ni * 16 + mr;
        float v = acc[mi][ni][r] + bias[gcol];
        float sg = 1.0f / (1.0f + __expf(-v));
        if (gcol < 128) {
          z[(size_t)grow * D + gcol] = __float2half(sg);
        } else {
          int cc = gcol - 128;
          float hv = bf2f(hl[(size_t)grow * D + cc]);
          rh[(size_t)grow * D + cc] = f2bf(sg * hv);
        }
      }
}

// GEMM2: out = z*h + (1-z)*tanh(pre); out dtype per flag; bf16 shadow into nextb (fp32 mode)
__global__ __launch_bounds__(256) void gemm2_kernel(
    const bf16* A0, const bf16* A1a, const bf16* A1b, const bf16* A2, const bf16* A3,
    const bf16* A3hA, const bf16* A3hB, const int* __restrict__ flag, const bf16* __restrict__ Bp,
    const float* __restrict__ bias, const __half* __restrict__ z, void* __restrict__ outbase,
    size_t lND, bf16* __restrict__ nextb, int M) {
  int fl = flag[0];
  const bf16* A1 = fl ? A1b : A1a;
  const bf16* hl = fl ? A3hB : A3hA;
  __shared__ bf16 As[BM * LDK];
  __shared__ bf16 Bs[BN * LDK];
  f32x4 acc[4][4];
#pragma unroll
  for (int i = 0; i < 4; ++i)
#pragma unroll
    for (int j = 0; j < 4; ++j) acc[i][j] = (f32x4){0.f, 0.f, 0.f, 0.f};
  int row0 = blockIdx.x * BM, col0 = 0;
  gemm_mainloop(A0, A1, A2, A3, Bp, M, row0, col0, As, Bs, acc);
  int lane = threadIdx.x & 63, wave = threadIdx.x >> 6;
  int wrow = (wave >> 1) * 64, wcol = (wave & 1) * 64;
  int mr = lane & 15, quad = lane >> 4;
#pragma unroll
  for (int mi = 0; mi < 4; ++mi)
#pragma unroll
    for (int ni = 0; ni < 4; ++ni)
#pragma unroll
      for (int r = 0; r < 4; ++r) {
        int grow = row0 + wrow + mi * 16 + quad * 4 + r;
        if (grow >= M) continue;
        int gcol = col0 + wcol + ni * 16 + mr;
        float pre = acc[mi][ni][r] + bias[gcol];
        float ht = tanhf(pre);
        size_t off = (size_t)grow * D + gcol;
        float zv = __half2float(z[off]);
        float hv = bf2f(hl[off]);
        float ov = zv * hv + (1.0f - zv) * ht;
        if (fl) {
          ((float*)outbase)[lND + off] = ov;
          nextb[off] = f2bf(ov);
        } else {
          ((bf16*)outbase)[lND + off] = f2bf(ov);
        }
      }
}

// ---------------- launch ----------------

extern "C" void kernel_launch(void* const* d_in, const int* in_sizes, int n_in, void* d_out,
                              int out_size, void* d_ws, size_t ws_size, hipStream_t stream) {
  const void* x = d_in[0];
  const void* h = d_in[1];
  const void* Wl = d_in[2];
  const void* Wr = d_in[3];
  const void* b = d_in[4];
  const int* src = (const int*)d_in[5];
  const int* dst = (const int*)d_in[6];

  const int NX = in_sizes[0];
  const int NH = in_sizes[1];
  const int N = NX / D;
  const int E = in_sizes[5];
  const int L = NH / NX;
  (void)n_in;
  (void)out_size;
  (void)ws_size;

  char* ws = (char*)d_ws;
  size_t off = 0;
  auto alloc = [&](size_t bytes) -> char* {
    char* p = ws + off;
    off = (off + bytes + 255) & ~(size_t)255;
    return p;
  };
  int* flag = (int*)alloc(256);
  int* deg = (int*)alloc((size_t)N * 4);
  int* offs = (int*)alloc((size_t)(N + 1) * 4);
  int* cursor = (int*)alloc((size_t)N * 4);
  float* inv_deg = (float*)alloc((size_t)N * 4);
  int* bsum = (int*)alloc(256 * 4);
  int* esrc = (int*)alloc((size_t)E * 4);
  bf16* agg_inp = (bf16*)alloc((size_t)N * D * 2);
  bf16* agg2 = (bf16*)alloc((size_t)N * D * 2);
  bf16* rh = (bf16*)alloc((size_t)N * D * 2);
  __half* z = (__half*)alloc((size_t)N * D * 2);
  bf16* B1p = (bf16*)alloc(256 * 512 * 2);
  bf16* B2p = (bf16*)alloc(128 * 512 * 2);
  float* bs1 = (float*)alloc(256 * 4);
  float* bs2 = (float*)alloc(128 * 4);
  bf16* xb = (bf16*)alloc((size_t)NX * 2);  // fp32 mode only
  bf16* hb = (bf16*)alloc((size_t)NH * 2);  // fp32 mode only

  probe_kernel<<<1, 256, 0, stream>>>((const unsigned short*)Wl, in_sizes[2], flag);
  int ncv = NX > NH ? NX : NH;
  convert_kernel<<<(ncv + 255) / 256, 256, 0, stream>>>((const float*)x, (const float*)h, xb, hb,
                                                        flag, NX, NH);

  zero_int_kernel<<<(N + 255) / 256, 256, 0, stream>>>(deg, N);
  count_deg_kernel<<<(E + 255) / 256, 256, 0, stream>>>(dst, deg, E);
  int nb = (N + SCAN_BLK - 1) / SCAN_BLK;  // 49 for N=50000; scan2 handles nb<=256
  scan1_kernel<<<nb, 256, 0, stream>>>(deg, bsum, N);
  scan2_kernel<<<1, 256, 0, stream>>>(bsum, nb);
  scan3_kernel<<<nb, 256, 0, stream>>>(deg, bsum, offs, cursor, inv_deg, N, E);
  scatter_kernel<<<(E + 255) / 256, 256, 0, stream>>>(src, dst, cursor, esrc, E);

  int mtiles = (N + BM - 1) / BM;
  const int pack_elems = 256 * 512 + 128 * 512 + 384;
  for (int l = 0; l < L; ++l) {
    const size_t lND = (size_t)l * N * D;
    const bf16* inpA = (l == 0) ? (const bf16*)x : ((const bf16*)d_out + lND - (size_t)N * D);
    const bf16* hlA = (const bf16*)h + lND;
    const bf16* hlB = hb + lND;

    pack_kernel<<<(pack_elems + 255) / 256, 256, 0, stream>>>(Wl, Wr, b, l, flag, B1p, B2p, bs1,
                                                              bs2);
    agg_dual_kernel<<<(N + 3) / 4, 256, 0, stream>>>(inpA, xb, hlA, hlB, flag, esrc, offs, inv_deg,
                                                     agg_inp, agg2, N);
    gemm1_kernel<<<dim3(mtiles, 2), 256, 0, stream>>>(agg_inp, inpA, xb, agg2, hlA, hlB, flag, B1p,
                                                      bs1, z, rh, N);
    agg_kernel<<<(N + 3) / 4, 256, 0, stream>>>(rh, rh, flag, esrc, offs, inv_deg, agg2, N);
    gemm2_kernel<<<dim3(mtiles, 1), 256, 0, stream>>>(agg_inp, inpA, xb, agg2, rh, hlA, hlB, flag,
                                                      B2p, bs2, z, d_out, lND, xb, N);
  }
}

// Round 4
// 672.215 us; speedup vs baseline: 1.6024x; 1.2366x over previous
//
#include <hip/hip_runtime.h>
#include <hip/hip_bf16.h>
#include <hip/hip_fp16.h>

#define D 128
#define BM 128
#define BN 128
#define LDK 72  // padded LDS k-stride (bf16 elems): 144B rows -> 2-way bank aliasing only (free)
#define SCAN_BLK 1024  // elements per scan block (256 thr x 4)

typedef __attribute__((ext_vector_type(8))) __bf16 bf16x8;
typedef __attribute__((ext_vector_type(4))) float f32x4;
typedef __hip_bfloat16 bf16;

__device__ __forceinline__ float bf2f(bf16 v) { return __bfloat162float(v); }
__device__ __forceinline__ bf16 f2bf(float v) { return __float2bfloat16(v); }

// ---------------- dtype probe: are the float tensors bf16 or fp32? ----------------
__global__ void probe_kernel(const unsigned short* __restrict__ w, int n, int* __restrict__ flag) {
  __shared__ int cnt[256];
  int t = threadIdx.x;
  int bad = 0;
  int lim = n < 65536 ? n : 65536;
  for (int i = t; i < lim; i += 256) {
    unsigned int u = ((unsigned int)w[i]) << 16;
    float v = __uint_as_float(u);
    if (!(fabsf(v) <= 4.0f)) bad++;  // catches NaN too
  }
  cnt[t] = bad;
  __syncthreads();
  for (int off = 128; off > 0; off >>= 1) {
    if (t < off) cnt[t] += cnt[t + off];
    __syncthreads();
  }
  if (t == 0) flag[0] = (cnt[0] > 2048) ? 1 : 0;
}

// fp32 mode only: materialize canonical bf16 copies of x and h.
__global__ void convert_kernel(const float* __restrict__ xf, const float* __restrict__ hf,
                               bf16* __restrict__ xb, bf16* __restrict__ hb,
                               const int* __restrict__ flag, int nx, int nh) {
  if (flag[0] == 0) return;
  int i = blockIdx.x * blockDim.x + threadIdx.x;
  if (i < nx) xb[i] = f2bf(xf[i]);
  if (i < nh) hb[i] = f2bf(hf[i]);
}

// ---------------- graph preprocessing ----------------

__global__ void zero_int_kernel(int* p, int n) {
  int i = blockIdx.x * blockDim.x + threadIdx.x;
  if (i < n) p[i] = 0;
}

__global__ void count_deg_kernel(const int* __restrict__ dst, int* __restrict__ deg, int E) {
  int e = blockIdx.x * blockDim.x + threadIdx.x;
  if (e < E) atomicAdd(&deg[dst[e]], 1);
}

// phase 1: per-block sums of 1024 deg values
__global__ void scan1_kernel(const int* __restrict__ deg, int* __restrict__ bsum, int N) {
  __shared__ int lsum[256];
  int t = threadIdx.x;
  int base = blockIdx.x * SCAN_BLK + t * 4;
  int s = 0;
  if (base + 3 < N) {
    int4 v = *(const int4*)(deg + base);
    s = v.x + v.y + v.z + v.w;
  } else {
    for (int i = 0; i < 4; ++i)
      if (base + i < N) s += deg[base + i];
  }
  lsum[t] = s;
  __syncthreads();
  for (int off = 128; off > 0; off >>= 1) {
    if (t < off) lsum[t] += lsum[t + off];
    __syncthreads();
  }
  if (t == 0) bsum[blockIdx.x] = lsum[0];
}

// phase 2: exclusive scan of block sums (nb <= 256), single block
__global__ void scan2_kernel(int* __restrict__ bsum, int nb) {
  __shared__ int sh[256];
  int t = threadIdx.x;
  sh[t] = (t < nb) ? bsum[t] : 0;
  __syncthreads();
  for (int off = 1; off < 256; off <<= 1) {
    int v = sh[t];
    int add = (t >= off) ? sh[t - off] : 0;
    __syncthreads();
    sh[t] = v + add;
    __syncthreads();
  }
  if (t < nb) bsum[t] = (t == 0) ? 0 : sh[t - 1];
}

// phase 3: per-block local scan + block offset -> offs/cursor/inv_deg
__global__ void scan3_kernel(const int* __restrict__ deg, const int* __restrict__ bsum,
                             int* __restrict__ offs, int* __restrict__ cursor,
                             float* __restrict__ inv_deg, int N, int E) {
  __shared__ int lsum[256];
  int t = threadIdx.x;
  int base = blockIdx.x * SCAN_BLK + t * 4;
  int d0 = 0, d1 = 0, d2 = 0, d3 = 0;
  if (base + 3 < N) {
    int4 v = *(const int4*)(deg + base);
    d0 = v.x; d1 = v.y; d2 = v.z; d3 = v.w;
  } else {
    if (base + 0 < N) d0 = deg[base + 0];
    if (base + 1 < N) d1 = deg[base + 1];
    if (base + 2 < N) d2 = deg[base + 2];
    if (base + 3 < N) d3 = deg[base + 3];
  }
  lsum[t] = d0 + d1 + d2 + d3;
  __syncthreads();
  for (int off = 1; off < 256; off <<= 1) {
    int v = lsum[t];
    int add = (t >= off) ? lsum[t - off] : 0;
    __syncthreads();
    lsum[t] = v + add;
    __syncthreads();
  }
  int run = bsum[blockIdx.x] + ((t == 0) ? 0 : lsum[t - 1]);
  int dd[4] = {d0, d1, d2, d3};
  for (int i = 0; i < 4; ++i) {
    int idx = base + i;
    if (idx < N) {
      offs[idx] = run;
      cursor[idx] = run;
      inv_deg[idx] = 1.0f / (float)(dd[i] > 1 ? dd[i] : 1);
      run += dd[i];
    }
  }
  if (blockIdx.x == 0 && t == 0) offs[N] = E;
}

__global__ void scatter_kernel(const int* __restrict__ src, const int* __restrict__ dst,
                               int* __restrict__ cursor, int* __restrict__ esrc, int E) {
  int e = blockIdx.x * blockDim.x + threadIdx.x;
  if (e < E) {
    int pos = atomicAdd(&cursor[dst[e]], 1);
    esrc[pos] = src[e];
  }
}

// ---------------- mean aggregation (CSR gather, one wave per node) ----------------
// ILP strategy: one coalesced load of up to 64 edge indices per wave, broadcast
// via __shfl, process edges in groups (8 outstanding row loads) to cover the
// ~200-900 cyc global-load latency.

__global__ void agg_kernel(const bf16* __restrict__ featA, const bf16* __restrict__ featB,
                           const int* __restrict__ flag, const int* __restrict__ esrc,
                           const int* __restrict__ offs, const float* __restrict__ inv_deg,
                           bf16* __restrict__ out, int N) {
  const bf16* feat = flag[0] ? featB : featA;
  int node = (int)((blockIdx.x * (size_t)blockDim.x + threadIdx.x) >> 6);
  int lane = threadIdx.x & 63;
  if (node >= N) return;
  int e0 = offs[node], e1 = offs[node + 1];
  float a0 = 0.f, a1 = 0.f;
  int c = lane * 2;
  for (int base = e0; base < e1; base += 64) {
    int cnt = e1 - base;
    if (cnt > 64) cnt = 64;
    int ei = base + lane;
    int idx = esrc[ei < e1 ? ei : (e1 - 1)];
    int j = 0;
    for (; j + 8 <= cnt; j += 8) {
      int s0 = __shfl(idx, j + 0, 64), s1 = __shfl(idx, j + 1, 64);
      int s2 = __shfl(idx, j + 2, 64), s3 = __shfl(idx, j + 3, 64);
      int s4 = __shfl(idx, j + 4, 64), s5 = __shfl(idx, j + 5, 64);
      int s6 = __shfl(idx, j + 6, 64), s7 = __shfl(idx, j + 7, 64);
      __hip_bfloat162 v0 = *(const __hip_bfloat162*)(feat + (size_t)s0 * D + c);
      __hip_bfloat162 v1 = *(const __hip_bfloat162*)(feat + (size_t)s1 * D + c);
      __hip_bfloat162 v2 = *(const __hip_bfloat162*)(feat + (size_t)s2 * D + c);
      __hip_bfloat162 v3 = *(const __hip_bfloat162*)(feat + (size_t)s3 * D + c);
      __hip_bfloat162 v4 = *(const __hip_bfloat162*)(feat + (size_t)s4 * D + c);
      __hip_bfloat162 v5 = *(const __hip_bfloat162*)(feat + (size_t)s5 * D + c);
      __hip_bfloat162 v6 = *(const __hip_bfloat162*)(feat + (size_t)s6 * D + c);
      __hip_bfloat162 v7 = *(const __hip_bfloat162*)(feat + (size_t)s7 * D + c);
      a0 += bf2f(v0.x) + bf2f(v1.x) + bf2f(v2.x) + bf2f(v3.x) +
            bf2f(v4.x) + bf2f(v5.x) + bf2f(v6.x) + bf2f(v7.x);
      a1 += bf2f(v0.y) + bf2f(v1.y) + bf2f(v2.y) + bf2f(v3.y) +
            bf2f(v4.y) + bf2f(v5.y) + bf2f(v6.y) + bf2f(v7.y);
    }
    for (; j < cnt; ++j) {
      int s = __shfl(idx, j, 64);
      __hip_bfloat162 v = *(const __hip_bfloat162*)(feat + (size_t)s * D + c);
      a0 += bf2f(v.x);
      a1 += bf2f(v.y);
    }
  }
  float w = inv_deg[node];
  __hip_bfloat162 o;
  o.x = f2bf(a0 * w);
  o.y = f2bf(a1 * w);
  *(__hip_bfloat162*)(out + (size_t)node * D + c) = o;
}

// dual gather: aggregate two feature matrices over the same edge walk (4-edge
// groups -> 8 outstanding row loads)
__global__ void agg_dual_kernel(const bf16* __restrict__ fAa, const bf16* __restrict__ fAb,
                                const bf16* __restrict__ fBa, const bf16* __restrict__ fBb,
                                const int* __restrict__ flag, const int* __restrict__ esrc,
                                const int* __restrict__ offs, const float* __restrict__ inv_deg,
                                bf16* __restrict__ outA, bf16* __restrict__ outB, int N) {
  int fl = flag[0];
  const bf16* fA = fl ? fAb : fAa;
  const bf16* fB = fl ? fBb : fBa;
  int node = (int)((blockIdx.x * (size_t)blockDim.x + threadIdx.x) >> 6);
  int lane = threadIdx.x & 63;
  if (node >= N) return;
  int e0 = offs[node], e1 = offs[node + 1];
  float a0 = 0.f, a1 = 0.f, b0 = 0.f, b1 = 0.f;
  int c = lane * 2;
  for (int base = e0; base < e1; base += 64) {
    int cnt = e1 - base;
    if (cnt > 64) cnt = 64;
    int ei = base + lane;
    int idx = esrc[ei < e1 ? ei : (e1 - 1)];
    int j = 0;
    for (; j + 4 <= cnt; j += 4) {
      int s0 = __shfl(idx, j + 0, 64), s1 = __shfl(idx, j + 1, 64);
      int s2 = __shfl(idx, j + 2, 64), s3 = __shfl(idx, j + 3, 64);
      size_t r0 = (size_t)s0 * D + c, r1 = (size_t)s1 * D + c;
      size_t r2 = (size_t)s2 * D + c, r3 = (size_t)s3 * D + c;
      __hip_bfloat162 va0 = *(const __hip_bfloat162*)(fA + r0);
      __hip_bfloat162 va1 = *(const __hip_bfloat162*)(fA + r1);
      __hip_bfloat162 va2 = *(const __hip_bfloat162*)(fA + r2);
      __hip_bfloat162 va3 = *(const __hip_bfloat162*)(fA + r3);
      __hip_bfloat162 vb0 = *(const __hip_bfloat162*)(fB + r0);
      __hip_bfloat162 vb1 = *(const __hip_bfloat162*)(fB + r1);
      __hip_bfloat162 vb2 = *(const __hip_bfloat162*)(fB + r2);
      __hip_bfloat162 vb3 = *(const __hip_bfloat162*)(fB + r3);
      a0 += bf2f(va0.x) + bf2f(va1.x) + bf2f(va2.x) + bf2f(va3.x);
      a1 += bf2f(va0.y) + bf2f(va1.y) + bf2f(va2.y) + bf2f(va3.y);
      b0 += bf2f(vb0.x) + bf2f(vb1.x) + bf2f(vb2.x) + bf2f(vb3.x);
      b1 += bf2f(vb0.y) + bf2f(vb1.y) + bf2f(vb2.y) + bf2f(vb3.y);
    }
    for (; j < cnt; ++j) {
      int s = __shfl(idx, j, 64);
      size_t ro = (size_t)s * D + c;
      __hip_bfloat162 va = *(const __hip_bfloat162*)(fA + ro);
      __hip_bfloat162 vb = *(const __hip_bfloat162*)(fB + ro);
      a0 += bf2f(va.x);
      a1 += bf2f(va.y);
      b0 += bf2f(vb.x);
      b1 += bf2f(vb.y);
    }
  }
  float w = inv_deg[node];
  __hip_bfloat162 oa, ob;
  oa.x = f2bf(a0 * w);
  oa.y = f2bf(a1 * w);
  ob.x = f2bf(b0 * w);
  ob.y = f2bf(b1 * w);
  *(__hip_bfloat162*)(outA + (size_t)node * D + c) = oa;
  *(__hip_bfloat162*)(outB + (size_t)node * D + c) = ob;
}

// ---------------- weight packing: B^T layout [n][k], k = 4 blocks of 128 ----------------

__device__ __forceinline__ float loadw(const void* p, size_t idx, int fl) {
  return fl ? ((const float*)p)[idx] : bf2f(((const bf16*)p)[idx]);
}

__global__ void pack_kernel(const void* __restrict__ Wl, const void* __restrict__ Wr,
                            const void* __restrict__ b, int l, const int* __restrict__ flag,
                            bf16* __restrict__ B1p, bf16* __restrict__ B2p,
                            float* __restrict__ bs1, float* __restrict__ bs2) {
  int fl = flag[0];
  int idx = blockIdx.x * blockDim.x + threadIdx.x;
  const int SZ1 = 256 * 512;
  const int SZ2 = 128 * 512;
  if (idx < SZ1) {
    int n = idx >> 9, k = idx & 511;
    int p = k >> 7, kr = k & 127;
    int gpair = n >> 7, nc = n & 127;
    int gate = gpair * 2 + (p >> 1);
    const void* W = (p & 1) ? Wr : Wl;
    B1p[idx] = f2bf(loadw(W, (((size_t)l * 6 + gate) * D + kr) * D + nc, fl));
  } else if (idx < SZ1 + SZ2) {
    int i2 = idx - SZ1;
    int n = i2 >> 9, k = i2 & 511;
    int p = k >> 7, kr = k & 127;
    int gate = 4 + (p >> 1);
    const void* W = (p & 1) ? Wr : Wl;
    B2p[i2] = f2bf(loadw(W, (((size_t)l * 6 + gate) * D + kr) * D + n, fl));
  } else if (idx < SZ1 + SZ2 + 384) {
    int c = idx - (SZ1 + SZ2);
    if (c < 256) {
      int g0 = (c >> 7) * 2;
      int cc = c & 127;
      bs1[c] = loadw(b, ((size_t)l * 6 + g0) * D + cc, fl) +
               loadw(b, ((size_t)l * 6 + g0 + 1) * D + cc, fl);
    } else {
      int cc = c - 256;
      bs2[cc] = loadw(b, ((size_t)l * 6 + 4) * D + cc, fl) +
                loadw(b, ((size_t)l * 6 + 5) * D + cc, fl);
    }
  }
}

// ---------------- MFMA GEMM mainloop: C[128x128] = A[128x512] @ B[512x128] ----------------

__device__ __forceinline__ void gemm_mainloop(const bf16* A0, const bf16* A1, const bf16* A2,
                                              const bf16* A3, const bf16* __restrict__ Bp, int M,
                                              int row0, int col0, bf16* As, bf16* Bs,
                                              f32x4 (&acc)[4][4]) {
  int tid = threadIdx.x;
  int wave = tid >> 6, lane = tid & 63;
  int wrow = (wave >> 1) * 64, wcol = (wave & 1) * 64;
  const bf16* Ablk[4] = {A0, A1, A2, A3};
#pragma unroll
  for (int kt = 0; kt < 8; ++kt) {
    const int kglob = kt * 64;
    const bf16* Aptr = Ablk[kglob >> 7];
    const int kr = kglob & 127;
#pragma unroll
    for (int i = 0; i < 4; ++i) {
      int c = tid + i * 256;
      int r = c >> 3;
      int ko = (c & 7) * 8;
      int rg = row0 + r;
      if (rg > M - 1) rg = M - 1;  // clamp: garbage rows never stored
      uint4 va = *(const uint4*)(const void*)(Aptr + (size_t)rg * D + kr + ko);
      *(uint4*)(void*)(As + r * LDK + ko) = va;
      uint4 vb = *(const uint4*)(const void*)(Bp + (size_t)(col0 + r) * 512 + kglob + ko);
      *(uint4*)(void*)(Bs + r * LDK + ko) = vb;
    }
    __syncthreads();
#pragma unroll
    for (int kk = 0; kk < 2; ++kk) {
      int kb = kk * 32 + (lane >> 4) * 8;
      int mr = lane & 15;
      bf16x8 af[4], bfv[4];
#pragma unroll
      for (int mi = 0; mi < 4; ++mi)
        af[mi] = *(const bf16x8*)(const void*)(As + (wrow + mi * 16 + mr) * LDK + kb);
#pragma unroll
      for (int ni = 0; ni < 4; ++ni)
        bfv[ni] = *(const bf16x8*)(const void*)(Bs + (wcol + ni * 16 + mr) * LDK + kb);
#pragma unroll
      for (int mi = 0; mi < 4; ++mi)
#pragma unroll
        for (int ni = 0; ni < 4; ++ni)
          acc[mi][ni] =
              __builtin_amdgcn_mfma_f32_16x16x32_bf16(af[mi], bfv[ni], acc[mi][ni], 0, 0, 0);
    }
    __syncthreads();
  }
}

// GEMM1: cols 0..127 -> z = sigmoid(.) (fp16); cols 128..255 -> rh = sigmoid(.)*h (bf16)
__global__ __launch_bounds__(256) void gemm1_kernel(
    const bf16* A0, const bf16* A1a, const bf16* A1b, const bf16* A2, const bf16* A3a,
    const bf16* A3b, const int* __restrict__ flag, const bf16* __restrict__ Bp,
    const float* __restrict__ bias, __half* __restrict__ z, bf16* __restrict__ rh, int M) {
  int fl = flag[0];
  const bf16* A1 = fl ? A1b : A1a;
  const bf16* A3 = fl ? A3b : A3a;
  const bf16* hl = A3;
  __shared__ bf16 As[BM * LDK];
  __shared__ bf16 Bs[BN * LDK];
  f32x4 acc[4][4];
#pragma unroll
  for (int i = 0; i < 4; ++i)
#pragma unroll
    for (int j = 0; j < 4; ++j) acc[i][j] = (f32x4){0.f, 0.f, 0.f, 0.f};
  int row0 = blockIdx.x * BM, col0 = blockIdx.y * BN;
  gemm_mainloop(A0, A1, A2, A3, Bp, M, row0, col0, As, Bs, acc);
  int lane = threadIdx.x & 63, wave = threadIdx.x >> 6;
  int wrow = (wave >> 1) * 64, wcol = (wave & 1) * 64;
  int mr = lane & 15, quad = lane >> 4;
#pragma unroll
  for (int mi = 0; mi < 4; ++mi)
#pragma unroll
    for (int ni = 0; ni < 4; ++ni)
#pragma unroll
      for (int r = 0; r < 4; ++r) {
        int grow = row0 + wrow + mi * 16 + quad * 4 + r;
        if (grow >= M) continue;
        int gcol = col0 + wcol + ni * 16 + mr;
        float v = acc[mi][ni][r] + bias[gcol];
        float sg = 1.0f / (1.0f + __expf(-v));
        if (gcol < 128) {
          z[(size_t)grow * D + gcol] = __float2half(sg);
        } else {
          int cc = gcol - 128;
          float hv = bf2f(hl[(size_t)grow * D + cc]);
          rh[(size_t)grow * D + cc] = f2bf(sg * hv);
        }
      }
}

// GEMM2: out = z*h + (1-z)*tanh(pre); out dtype per flag; bf16 shadow into nextb (fp32 mode)
__global__ __launch_bounds__(256) void gemm2_kernel(
    const bf16* A0, const bf16* A1a, const bf16* A1b, const bf16* A2, const bf16* A3,
    const bf16* A3hA, const bf16* A3hB, const int* __restrict__ flag, const bf16* __restrict__ Bp,
    const float* __restrict__ bias, const __half* __restrict__ z, void* __restrict__ outbase,
    size_t lND, bf16* __restrict__ nextb, int M) {
  int fl = flag[0];
  const bf16* A1 = fl ? A1b : A1a;
  const bf16* hl = fl ? A3hB : A3hA;
  __shared__ bf16 As[BM * LDK];
  __shared__ bf16 Bs[BN * LDK];
  f32x4 acc[4][4];
#pragma unroll
  for (int i = 0; i < 4; ++i)
#pragma unroll
    for (int j = 0; j < 4; ++j) acc[i][j] = (f32x4){0.f, 0.f, 0.f, 0.f};
  int row0 = blockIdx.x * BM, col0 = 0;
  gemm_mainloop(A0, A1, A2, A3, Bp, M, row0, col0, As, Bs, acc);
  int lane = threadIdx.x & 63, wave = threadIdx.x >> 6;
  int wrow = (wave >> 1) * 64, wcol = (wave & 1) * 64;
  int mr = lane & 15, quad = lane >> 4;
#pragma unroll
  for (int mi = 0; mi < 4; ++mi)
#pragma unroll
    for (int ni = 0; ni < 4; ++ni)
#pragma unroll
      for (int r = 0; r < 4; ++r) {
        int grow = row0 + wrow + mi * 16 + quad * 4 + r;
        if (grow >= M) continue;
        int gcol = col0 + wcol + ni * 16 + mr;
        float pre = acc[mi][ni][r] + bias[gcol];
        float ht = tanhf(pre);
        size_t off = (size_t)grow * D + gcol;
        float zv = __half2float(z[off]);
        float hv = bf2f(hl[off]);
        float ov = zv * hv + (1.0f - zv) * ht;
        if (fl) {
          ((float*)outbase)[lND + off] = ov;
          nextb[off] = f2bf(ov);
        } else {
          ((bf16*)outbase)[lND + off] = f2bf(ov);
        }
      }
}

// ---------------- launch ----------------

extern "C" void kernel_launch(void* const* d_in, const int* in_sizes, int n_in, void* d_out,
                              int out_size, void* d_ws, size_t ws_size, hipStream_t stream) {
  const void* x = d_in[0];
  const void* h = d_in[1];
  const void* Wl = d_in[2];
  const void* Wr = d_in[3];
  const void* b = d_in[4];
  const int* src = (const int*)d_in[5];
  const int* dst = (const int*)d_in[6];

  const int NX = in_sizes[0];
  const int NH = in_sizes[1];
  const int N = NX / D;
  const int E = in_sizes[5];
  const int L = NH / NX;
  (void)n_in;
  (void)out_size;
  (void)ws_size;

  char* ws = (char*)d_ws;
  size_t off = 0;
  auto alloc = [&](size_t bytes) -> char* {
    char* p = ws + off;
    off = (off + bytes + 255) & ~(size_t)255;
    return p;
  };
  int* flag = (int*)alloc(256);
  int* deg = (int*)alloc((size_t)N * 4);
  int* offs = (int*)alloc((size_t)(N + 1) * 4);
  int* cursor = (int*)alloc((size_t)N * 4);
  float* inv_deg = (float*)alloc((size_t)N * 4);
  int* bsum = (int*)alloc(256 * 4);
  int* esrc = (int*)alloc((size_t)E * 4);
  bf16* agg_inp = (bf16*)alloc((size_t)N * D * 2);
  bf16* agg2 = (bf16*)alloc((size_t)N * D * 2);
  bf16* rh = (bf16*)alloc((size_t)N * D * 2);
  __half* z = (__half*)alloc((size_t)N * D * 2);
  bf16* B1p = (bf16*)alloc(256 * 512 * 2);
  bf16* B2p = (bf16*)alloc(128 * 512 * 2);
  float* bs1 = (float*)alloc(256 * 4);
  float* bs2 = (float*)alloc(128 * 4);
  bf16* xb = (bf16*)alloc((size_t)NX * 2);  // fp32 mode only
  bf16* hb = (bf16*)alloc((size_t)NH * 2);  // fp32 mode only

  probe_kernel<<<1, 256, 0, stream>>>((const unsigned short*)Wl, in_sizes[2], flag);
  int ncv = NX > NH ? NX : NH;
  convert_kernel<<<(ncv + 255) / 256, 256, 0, stream>>>((const float*)x, (const float*)h, xb, hb,
                                                        flag, NX, NH);

  zero_int_kernel<<<(N + 255) / 256, 256, 0, stream>>>(deg, N);
  count_deg_kernel<<<(E + 255) / 256, 256, 0, stream>>>(dst, deg, E);
  int nb = (N + SCAN_BLK - 1) / SCAN_BLK;  // 49 for N=50000; scan2 handles nb<=256
  scan1_kernel<<<nb, 256, 0, stream>>>(deg, bsum, N);
  scan2_kernel<<<1, 256, 0, stream>>>(bsum, nb);
  scan3_kernel<<<nb, 256, 0, stream>>>(deg, bsum, offs, cursor, inv_deg, N, E);
  scatter_kernel<<<(E + 255) / 256, 256, 0, stream>>>(src, dst, cursor, esrc, E);

  int mtiles = (N + BM - 1) / BM;
  const int pack_elems = 256 * 512 + 128 * 512 + 384;
  for (int l = 0; l < L; ++l) {
    const size_t lND = (size_t)l * N * D;
    const bf16* inpA = (l == 0) ? (const bf16*)x : ((const bf16*)d_out + lND - (size_t)N * D);
    const bf16* hlA = (const bf16*)h + lND;
    const bf16* hlB = hb + lND;

    pack_kernel<<<(pack_elems + 255) / 256, 256, 0, stream>>>(Wl, Wr, b, l, flag, B1p, B2p, bs1,
                                                              bs2);
    agg_dual_kernel<<<(N + 3) / 4, 256, 0, stream>>>(inpA, xb, hlA, hlB, flag, esrc, offs, inv_deg,
                                                     agg_inp, agg2, N);
    gemm1_kernel<<<dim3(mtiles, 2), 256, 0, stream>>>(agg_inp, inpA, xb, agg2, hlA, hlB, flag, B1p,
                                                      bs1, z, rh, N);
    agg_kernel<<<(N + 3) / 4, 256, 0, stream>>>(rh, rh, flag, esrc, offs, inv_deg, agg2, N);
    gemm2_kernel<<<dim3(mtiles, 1), 256, 0, stream>>>(agg_inp, inpA, xb, agg2, rh, hlA, hlB, flag,
                                                      B2p, bs2, z, d_out, lND, xb, N);
  }
}

// Round 5
// 661.300 us; speedup vs baseline: 1.6289x; 1.0165x over previous
//
#include <hip/hip_runtime.h>
#include <hip/hip_bf16.h>
#include <hip/hip_fp16.h>

#define D 128
#define BM 128
#define BN 128
#define LDSK 64  // unpadded k-stride; bank conflicts handled by XOR granule swizzle
#define SCAN_BLK 1024  // elements per scan block (256 thr x 4)

#define GLOBAL_AS __attribute__((address_space(1)))
#define LDS_AS __attribute__((address_space(3)))

typedef __attribute__((ext_vector_type(8))) __bf16 bf16x8;
typedef __attribute__((ext_vector_type(4))) float f32x4;
typedef __hip_bfloat16 bf16;

__device__ __forceinline__ float bf2f(bf16 v) { return __bfloat162float(v); }
__device__ __forceinline__ bf16 f2bf(float v) { return __float2bfloat16(v); }

// ---------------- dtype probe: are the float tensors bf16 or fp32? ----------------
__global__ void probe_kernel(const unsigned short* __restrict__ w, int n, int* __restrict__ flag) {
  __shared__ int cnt[256];
  int t = threadIdx.x;
  int bad = 0;
  int lim = n < 65536 ? n : 65536;
  for (int i = t; i < lim; i += 256) {
    unsigned int u = ((unsigned int)w[i]) << 16;
    float v = __uint_as_float(u);
    if (!(fabsf(v) <= 4.0f)) bad++;  // catches NaN too
  }
  cnt[t] = bad;
  __syncthreads();
  for (int off = 128; off > 0; off >>= 1) {
    if (t < off) cnt[t] += cnt[t + off];
    __syncthreads();
  }
  if (t == 0) flag[0] = (cnt[0] > 2048) ? 1 : 0;
}

// fp32 mode only: materialize canonical bf16 copies of x and h.
__global__ void convert_kernel(const float* __restrict__ xf, const float* __restrict__ hf,
                               bf16* __restrict__ xb, bf16* __restrict__ hb,
                               const int* __restrict__ flag, int nx, int nh) {
  if (flag[0] == 0) return;
  int i = blockIdx.x * blockDim.x + threadIdx.x;
  if (i < nx) xb[i] = f2bf(xf[i]);
  if (i < nh) hb[i] = f2bf(hf[i]);
}

// ---------------- graph preprocessing ----------------

__global__ void zero_int_kernel(int* p, int n) {
  int i = blockIdx.x * blockDim.x + threadIdx.x;
  if (i < n) p[i] = 0;
}

__global__ void count_deg_kernel(const int* __restrict__ dst, int* __restrict__ deg, int E) {
  int e = blockIdx.x * blockDim.x + threadIdx.x;
  if (e < E) atomicAdd(&deg[dst[e]], 1);
}

// phase 1: per-block sums of 1024 deg values
__global__ void scan1_kernel(const int* __restrict__ deg, int* __restrict__ bsum, int N) {
  __shared__ int lsum[256];
  int t = threadIdx.x;
  int base = blockIdx.x * SCAN_BLK + t * 4;
  int s = 0;
  if (base + 3 < N) {
    int4 v = *(const int4*)(deg + base);
    s = v.x + v.y + v.z + v.w;
  } else {
    for (int i = 0; i < 4; ++i)
      if (base + i < N) s += deg[base + i];
  }
  lsum[t] = s;
  __syncthreads();
  for (int off = 128; off > 0; off >>= 1) {
    if (t < off) lsum[t] += lsum[t + off];
    __syncthreads();
  }
  if (t == 0) bsum[blockIdx.x] = lsum[0];
}

// phase 2: exclusive scan of block sums (nb <= 256), single block
__global__ void scan2_kernel(int* __restrict__ bsum, int nb) {
  __shared__ int sh[256];
  int t = threadIdx.x;
  sh[t] = (t < nb) ? bsum[t] : 0;
  __syncthreads();
  for (int off = 1; off < 256; off <<= 1) {
    int v = sh[t];
    int add = (t >= off) ? sh[t - off] : 0;
    __syncthreads();
    sh[t] = v + add;
    __syncthreads();
  }
  if (t < nb) bsum[t] = (t == 0) ? 0 : sh[t - 1];
}

// phase 3: per-block local scan + block offset -> offs/cursor/inv_deg
__global__ void scan3_kernel(const int* __restrict__ deg, const int* __restrict__ bsum,
                             int* __restrict__ offs, int* __restrict__ cursor,
                             float* __restrict__ inv_deg, int N, int E) {
  __shared__ int lsum[256];
  int t = threadIdx.x;
  int base = blockIdx.x * SCAN_BLK + t * 4;
  int d0 = 0, d1 = 0, d2 = 0, d3 = 0;
  if (base + 3 < N) {
    int4 v = *(const int4*)(deg + base);
    d0 = v.x; d1 = v.y; d2 = v.z; d3 = v.w;
  } else {
    if (base + 0 < N) d0 = deg[base + 0];
    if (base + 1 < N) d1 = deg[base + 1];
    if (base + 2 < N) d2 = deg[base + 2];
    if (base + 3 < N) d3 = deg[base + 3];
  }
  lsum[t] = d0 + d1 + d2 + d3;
  __syncthreads();
  for (int off = 1; off < 256; off <<= 1) {
    int v = lsum[t];
    int add = (t >= off) ? lsum[t - off] : 0;
    __syncthreads();
    lsum[t] = v + add;
    __syncthreads();
  }
  int run = bsum[blockIdx.x] + ((t == 0) ? 0 : lsum[t - 1]);
  int dd[4] = {d0, d1, d2, d3};
  for (int i = 0; i < 4; ++i) {
    int idx = base + i;
    if (idx < N) {
      offs[idx] = run;
      cursor[idx] = run;
      inv_deg[idx] = 1.0f / (float)(dd[i] > 1 ? dd[i] : 1);
      run += dd[i];
    }
  }
  if (blockIdx.x == 0 && t == 0) offs[N] = E;
}

__global__ void scatter_kernel(const int* __restrict__ src, const int* __restrict__ dst,
                               int* __restrict__ cursor, int* __restrict__ esrc, int E) {
  int e = blockIdx.x * blockDim.x + threadIdx.x;
  if (e < E) {
    int pos = atomicAdd(&cursor[dst[e]], 1);
    esrc[pos] = src[e];
  }
}

// ---------------- mean aggregation (CSR gather, one wave per node) ----------------

__global__ void agg_kernel(const bf16* __restrict__ featA, const bf16* __restrict__ featB,
                           const int* __restrict__ flag, const int* __restrict__ esrc,
                           const int* __restrict__ offs, const float* __restrict__ inv_deg,
                           bf16* __restrict__ out, int N) {
  const bf16* feat = flag[0] ? featB : featA;
  int node = (int)((blockIdx.x * (size_t)blockDim.x + threadIdx.x) >> 6);
  int lane = threadIdx.x & 63;
  if (node >= N) return;
  int e0 = offs[node], e1 = offs[node + 1];
  float a0 = 0.f, a1 = 0.f;
  int c = lane * 2;
  for (int base = e0; base < e1; base += 64) {
    int cnt = e1 - base;
    if (cnt > 64) cnt = 64;
    int ei = base + lane;
    int idx = esrc[ei < e1 ? ei : (e1 - 1)];
    int j = 0;
    for (; j + 8 <= cnt; j += 8) {
      int s0 = __shfl(idx, j + 0, 64), s1 = __shfl(idx, j + 1, 64);
      int s2 = __shfl(idx, j + 2, 64), s3 = __shfl(idx, j + 3, 64);
      int s4 = __shfl(idx, j + 4, 64), s5 = __shfl(idx, j + 5, 64);
      int s6 = __shfl(idx, j + 6, 64), s7 = __shfl(idx, j + 7, 64);
      __hip_bfloat162 v0 = *(const __hip_bfloat162*)(feat + (size_t)s0 * D + c);
      __hip_bfloat162 v1 = *(const __hip_bfloat162*)(feat + (size_t)s1 * D + c);
      __hip_bfloat162 v2 = *(const __hip_bfloat162*)(feat + (size_t)s2 * D + c);
      __hip_bfloat162 v3 = *(const __hip_bfloat162*)(feat + (size_t)s3 * D + c);
      __hip_bfloat162 v4 = *(const __hip_bfloat162*)(feat + (size_t)s4 * D + c);
      __hip_bfloat162 v5 = *(const __hip_bfloat162*)(feat + (size_t)s5 * D + c);
      __hip_bfloat162 v6 = *(const __hip_bfloat162*)(feat + (size_t)s6 * D + c);
      __hip_bfloat162 v7 = *(const __hip_bfloat162*)(feat + (size_t)s7 * D + c);
      a0 += bf2f(v0.x) + bf2f(v1.x) + bf2f(v2.x) + bf2f(v3.x) +
            bf2f(v4.x) + bf2f(v5.x) + bf2f(v6.x) + bf2f(v7.x);
      a1 += bf2f(v0.y) + bf2f(v1.y) + bf2f(v2.y) + bf2f(v3.y) +
            bf2f(v4.y) + bf2f(v5.y) + bf2f(v6.y) + bf2f(v7.y);
    }
    for (; j < cnt; ++j) {
      int s = __shfl(idx, j, 64);
      __hip_bfloat162 v = *(const __hip_bfloat162*)(feat + (size_t)s * D + c);
      a0 += bf2f(v.x);
      a1 += bf2f(v.y);
    }
  }
  float w = inv_deg[node];
  __hip_bfloat162 o;
  o.x = f2bf(a0 * w);
  o.y = f2bf(a1 * w);
  *(__hip_bfloat162*)(out + (size_t)node * D + c) = o;
}

// dual gather: aggregate two feature matrices over the same edge walk
__global__ void agg_dual_kernel(const bf16* __restrict__ fAa, const bf16* __restrict__ fAb,
                                const bf16* __restrict__ fBa, const bf16* __restrict__ fBb,
                                const int* __restrict__ flag, const int* __restrict__ esrc,
                                const int* __restrict__ offs, const float* __restrict__ inv_deg,
                                bf16* __restrict__ outA, bf16* __restrict__ outB, int N) {
  int fl = flag[0];
  const bf16* fA = fl ? fAb : fAa;
  const bf16* fB = fl ? fBb : fBa;
  int node = (int)((blockIdx.x * (size_t)blockDim.x + threadIdx.x) >> 6);
  int lane = threadIdx.x & 63;
  if (node >= N) return;
  int e0 = offs[node], e1 = offs[node + 1];
  float a0 = 0.f, a1 = 0.f, b0 = 0.f, b1 = 0.f;
  int c = lane * 2;
  for (int base = e0; base < e1; base += 64) {
    int cnt = e1 - base;
    if (cnt > 64) cnt = 64;
    int ei = base + lane;
    int idx = esrc[ei < e1 ? ei : (e1 - 1)];
    int j = 0;
    for (; j + 4 <= cnt; j += 4) {
      int s0 = __shfl(idx, j + 0, 64), s1 = __shfl(idx, j + 1, 64);
      int s2 = __shfl(idx, j + 2, 64), s3 = __shfl(idx, j + 3, 64);
      size_t r0 = (size_t)s0 * D + c, r1 = (size_t)s1 * D + c;
      size_t r2 = (size_t)s2 * D + c, r3 = (size_t)s3 * D + c;
      __hip_bfloat162 va0 = *(const __hip_bfloat162*)(fA + r0);
      __hip_bfloat162 va1 = *(const __hip_bfloat162*)(fA + r1);
      __hip_bfloat162 va2 = *(const __hip_bfloat162*)(fA + r2);
      __hip_bfloat162 va3 = *(const __hip_bfloat162*)(fA + r3);
      __hip_bfloat162 vb0 = *(const __hip_bfloat162*)(fB + r0);
      __hip_bfloat162 vb1 = *(const __hip_bfloat162*)(fB + r1);
      __hip_bfloat162 vb2 = *(const __hip_bfloat162*)(fB + r2);
      __hip_bfloat162 vb3 = *(const __hip_bfloat162*)(fB + r3);
      a0 += bf2f(va0.x) + bf2f(va1.x) + bf2f(va2.x) + bf2f(va3.x);
      a1 += bf2f(va0.y) + bf2f(va1.y) + bf2f(va2.y) + bf2f(va3.y);
      b0 += bf2f(vb0.x) + bf2f(vb1.x) + bf2f(vb2.x) + bf2f(vb3.x);
      b1 += bf2f(vb0.y) + bf2f(vb1.y) + bf2f(vb2.y) + bf2f(vb3.y);
    }
    for (; j < cnt; ++j) {
      int s = __shfl(idx, j, 64);
      size_t ro = (size_t)s * D + c;
      __hip_bfloat162 va = *(const __hip_bfloat162*)(fA + ro);
      __hip_bfloat162 vb = *(const __hip_bfloat162*)(fB + ro);
      a0 += bf2f(va.x);
      a1 += bf2f(va.y);
      b0 += bf2f(vb.x);
      b1 += bf2f(vb.y);
    }
  }
  float w = inv_deg[node];
  __hip_bfloat162 oa, ob;
  oa.x = f2bf(a0 * w);
  oa.y = f2bf(a1 * w);
  ob.x = f2bf(b0 * w);
  ob.y = f2bf(b1 * w);
  *(__hip_bfloat162*)(outA + (size_t)node * D + c) = oa;
  *(__hip_bfloat162*)(outB + (size_t)node * D + c) = ob;
}

// ---------------- weight packing: B^T layout [n][k], k = 4 blocks of 128 ----------------

__device__ __forceinline__ float loadw(const void* p, size_t idx, int fl) {
  return fl ? ((const float*)p)[idx] : bf2f(((const bf16*)p)[idx]);
}

__global__ void pack_kernel(const void* __restrict__ Wl, const void* __restrict__ Wr,
                            const void* __restrict__ b, int l, const int* __restrict__ flag,
                            bf16* __restrict__ B1p, bf16* __restrict__ B2p,
                            float* __restrict__ bs1, float* __restrict__ bs2) {
  int fl = flag[0];
  int idx = blockIdx.x * blockDim.x + threadIdx.x;
  const int SZ1 = 256 * 512;
  const int SZ2 = 128 * 512;
  if (idx < SZ1) {
    int n = idx >> 9, k = idx & 511;
    int p = k >> 7, kr = k & 127;
    int gpair = n >> 7, nc = n & 127;
    int gate = gpair * 2 + (p >> 1);
    const void* W = (p & 1) ? Wr : Wl;
    B1p[idx] = f2bf(loadw(W, (((size_t)l * 6 + gate) * D + kr) * D + nc, fl));
  } else if (idx < SZ1 + SZ2) {
    int i2 = idx - SZ1;
    int n = i2 >> 9, k = i2 & 511;
    int p = k >> 7, kr = k & 127;
    int gate = 4 + (p >> 1);
    const void* W = (p & 1) ? Wr : Wl;
    B2p[i2] = f2bf(loadw(W, (((size_t)l * 6 + gate) * D + kr) * D + n, fl));
  } else if (idx < SZ1 + SZ2 + 384) {
    int c = idx - (SZ1 + SZ2);
    if (c < 256) {
      int g0 = (c >> 7) * 2;
      int cc = c & 127;
      bs1[c] = loadw(b, ((size_t)l * 6 + g0) * D + cc, fl) +
               loadw(b, ((size_t)l * 6 + g0 + 1) * D + cc, fl);
    } else {
      int cc = c - 256;
      bs2[cc] = loadw(b, ((size_t)l * 6 + 4) * D + cc, fl) +
                loadw(b, ((size_t)l * 6 + 5) * D + cc, fl);
    }
  }
}

// ---------------- MFMA GEMM mainloop: C[128x128] = A[128x512] @ B[512x128] ----------------
// global_load_lds (16B) staging with XOR granule swizzle: LDS granule (r, s)
// holds logical k-granule s^(r&7) of row r. Lane i of a wave-chunk writes
// base+i*16 (HW constraint), so lane i *fetches* global granule (i%8)^(i/8&7).

__device__ __forceinline__ void gemm_mainloop(const bf16* A0, const bf16* A1, const bf16* A2,
                                              const bf16* A3, const bf16* __restrict__ Bp, int M,
                                              int row0, int col0, bf16* As, bf16* Bs,
                                              f32x4 (&acc)[4][4]) {
  int tid = threadIdx.x;
  int wave = tid >> 6, lane = tid & 63;
  int wrow = (wave >> 1) * 64, wcol = (wave & 1) * 64;
  const bf16* Ablk[4] = {A0, A1, A2, A3};
  int r_rel = lane >> 3;  // 0..7 within the 8-row chunk
  int pslot = lane & 7;   // physical granule this lane writes
  int quad = lane >> 4, mr = lane & 15;
#pragma unroll
  for (int kt = 0; kt < 8; ++kt) {
    const bf16* Aptr = Ablk[kt >> 1];
    const int kr = (kt & 1) * 64;
#pragma unroll
    for (int i = 0; i < 4; ++i) {
      int rchunk = wave * 32 + i * 8;       // first row of this wave-instruction's chunk
      int r = rchunk + r_rel;               // tile row 0..127
      int gsrc = pslot ^ (r & 7);           // logical granule to fetch
      int rg = row0 + r;
      if (rg > M - 1) rg = M - 1;           // clamp: garbage rows never stored
      const bf16* ga = Aptr + (size_t)rg * D + kr + gsrc * 8;
      bf16* la = As + rchunk * LDSK;        // wave-uniform LDS base
      __builtin_amdgcn_global_load_lds((const GLOBAL_AS unsigned int*)(const void*)ga,
                                       (LDS_AS unsigned int*)(void*)la, 16, 0, 0);
      const bf16* gb = Bp + (size_t)(col0 + r) * 512 + kt * 64 + gsrc * 8;
      bf16* lb = Bs + rchunk * LDSK;
      __builtin_amdgcn_global_load_lds((const GLOBAL_AS unsigned int*)(const void*)gb,
                                       (LDS_AS unsigned int*)(void*)lb, 16, 0, 0);
    }
    __syncthreads();
#pragma unroll
    for (int kk = 0; kk < 2; ++kk) {
      int G = kk * 4 + quad;  // logical granule for this lane's fragment
      bf16x8 af[4], bfv[4];
#pragma unroll
      for (int mi = 0; mi < 4; ++mi) {
        int R = wrow + mi * 16 + mr;
        af[mi] = *(const bf16x8*)(const void*)(As + R * LDSK + ((G ^ (R & 7)) * 8));
      }
#pragma unroll
      for (int ni = 0; ni < 4; ++ni) {
        int R = wcol + ni * 16 + mr;
        bfv[ni] = *(const bf16x8*)(const void*)(Bs + R * LDSK + ((G ^ (R & 7)) * 8));
      }
#pragma unroll
      for (int mi = 0; mi < 4; ++mi)
#pragma unroll
        for (int ni = 0; ni < 4; ++ni)
          acc[mi][ni] =
              __builtin_amdgcn_mfma_f32_16x16x32_bf16(af[mi], bfv[ni], acc[mi][ni], 0, 0, 0);
    }
    __syncthreads();
  }
}

// GEMM1: cols 0..127 -> z = sigmoid(.) (fp16); cols 128..255 -> rh = sigmoid(.)*h (bf16)
__global__ __launch_bounds__(256) void gemm1_kernel(
    const bf16* A0, const bf16* A1a, const bf16* A1b, const bf16* A2, const bf16* A3a,
    const bf16* A3b, const int* __restrict__ flag, const bf16* __restrict__ Bp,
    const float* __restrict__ bias, __half* __restrict__ z, bf16* __restrict__ rh, int M) {
  int fl = flag[0];
  const bf16* A1 = fl ? A1b : A1a;
  const bf16* A3 = fl ? A3b : A3a;
  const bf16* hl = A3;
  __shared__ bf16 As[BM * LDSK];
  __shared__ bf16 Bs[BN * LDSK];
  f32x4 acc[4][4];
#pragma unroll
  for (int i = 0; i < 4; ++i)
#pragma unroll
    for (int j = 0; j < 4; ++j) acc[i][j] = (f32x4){0.f, 0.f, 0.f, 0.f};
  int row0 = blockIdx.x * BM, col0 = blockIdx.y * BN;
  gemm_mainloop(A0, A1, A2, A3, Bp, M, row0, col0, As, Bs, acc);
  int lane = threadIdx.x & 63, wave = threadIdx.x >> 6;
  int wrow = (wave >> 1) * 64, wcol = (wave & 1) * 64;
  int mr = lane & 15, quad = lane >> 4;
#pragma unroll
  for (int mi = 0; mi < 4; ++mi)
#pragma unroll
    for (int ni = 0; ni < 4; ++ni)
#pragma unroll
      for (int r = 0; r < 4; ++r) {
        int grow = row0 + wrow + mi * 16 + quad * 4 + r;
        if (grow >= M) continue;
        int gcol = col0 + wcol + ni * 16 + mr;
        float v = acc[mi][ni][r] + bias[gcol];
        float sg = 1.0f / (1.0f + __expf(-v));
        if (gcol < 128) {
          z[(size_t)grow * D + gcol] = __float2half(sg);
        } else {
          int cc = gcol - 128;
          float hv = bf2f(hl[(size_t)grow * D + cc]);
          rh[(size_t)grow * D + cc] = f2bf(sg * hv);
        }
      }
}

// GEMM2: out = z*h + (1-z)*tanh(pre); out dtype per flag; bf16 shadow into nextb (fp32 mode)
__global__ __launch_bounds__(256) void gemm2_kernel(
    const bf16* A0, const bf16* A1a, const bf16* A1b, const bf16* A2, const bf16* A3,
    const bf16* A3hA, const bf16* A3hB, const int* __restrict__ flag, const bf16* __restrict__ Bp,
    const float* __restrict__ bias, const __half* __restrict__ z, void* __restrict__ outbase,
    size_t lND, bf16* __restrict__ nextb, int M) {
  int fl = flag[0];
  const bf16* A1 = fl ? A1b : A1a;
  const bf16* hl = fl ? A3hB : A3hA;
  __shared__ bf16 As[BM * LDSK];
  __shared__ bf16 Bs[BN * LDSK];
  f32x4 acc[4][4];
#pragma unroll
  for (int i = 0; i < 4; ++i)
#pragma unroll
    for (int j = 0; j < 4; ++j) acc[i][j] = (f32x4){0.f, 0.f, 0.f, 0.f};
  int row0 = blockIdx.x * BM, col0 = 0;
  gemm_mainloop(A0, A1, A2, A3, Bp, M, row0, col0, As, Bs, acc);
  int lane = threadIdx.x & 63, wave = threadIdx.x >> 6;
  int wrow = (wave >> 1) * 64, wcol = (wave & 1) * 64;
  int mr = lane & 15, quad = lane >> 4;
#pragma unroll
  for (int mi = 0; mi < 4; ++mi)
#pragma unroll
    for (int ni = 0; ni < 4; ++ni)
#pragma unroll
      for (int r = 0; r < 4; ++r) {
        int grow = row0 + wrow + mi * 16 + quad * 4 + r;
        if (grow >= M) continue;
        int gcol = col0 + wcol + ni * 16 + mr;
        float pre = acc[mi][ni][r] + bias[gcol];
        float ht = tanhf(pre);
        size_t off = (size_t)grow * D + gcol;
        float zv = __half2float(z[off]);
        float hv = bf2f(hl[off]);
        float ov = zv * hv + (1.0f - zv) * ht;
        if (fl) {
          ((float*)outbase)[lND + off] = ov;
          nextb[off] = f2bf(ov);
        } else {
          ((bf16*)outbase)[lND + off] = f2bf(ov);
        }
      }
}

// ---------------- launch ----------------

extern "C" void kernel_launch(void* const* d_in, const int* in_sizes, int n_in, void* d_out,
                              int out_size, void* d_ws, size_t ws_size, hipStream_t stream) {
  const void* x = d_in[0];
  const void* h = d_in[1];
  const void* Wl = d_in[2];
  const void* Wr = d_in[3];
  const void* b = d_in[4];
  const int* src = (const int*)d_in[5];
  const int* dst = (const int*)d_in[6];

  const int NX = in_sizes[0];
  const int NH = in_sizes[1];
  const int N = NX / D;
  const int E = in_sizes[5];
  const int L = NH / NX;
  (void)n_in;
  (void)out_size;
  (void)ws_size;

  char* ws = (char*)d_ws;
  size_t off = 0;
  auto alloc = [&](size_t bytes) -> char* {
    char* p = ws + off;
    off = (off + bytes + 255) & ~(size_t)255;
    return p;
  };
  int* flag = (int*)alloc(256);
  int* deg = (int*)alloc((size_t)N * 4);
  int* offs = (int*)alloc((size_t)(N + 1) * 4);
  int* cursor = (int*)alloc((size_t)N * 4);
  float* inv_deg = (float*)alloc((size_t)N * 4);
  int* bsum = (int*)alloc(256 * 4);
  int* esrc = (int*)alloc((size_t)E * 4);
  bf16* agg_inp = (bf16*)alloc((size_t)N * D * 2);
  bf16* agg2 = (bf16*)alloc((size_t)N * D * 2);
  bf16* rh = (bf16*)alloc((size_t)N * D * 2);
  __half* z = (__half*)alloc((size_t)N * D * 2);
  bf16* B1p = (bf16*)alloc(256 * 512 * 2);
  bf16* B2p = (bf16*)alloc(128 * 512 * 2);
  float* bs1 = (float*)alloc(256 * 4);
  float* bs2 = (float*)alloc(128 * 4);
  bf16* xb = (bf16*)alloc((size_t)NX * 2);  // fp32 mode only
  bf16* hb = (bf16*)alloc((size_t)NH * 2);  // fp32 mode only

  probe_kernel<<<1, 256, 0, stream>>>((const unsigned short*)Wl, in_sizes[2], flag);
  int ncv = NX > NH ? NX : NH;
  convert_kernel<<<(ncv + 255) / 256, 256, 0, stream>>>((const float*)x, (const float*)h, xb, hb,
                                                        flag, NX, NH);

  zero_int_kernel<<<(N + 255) / 256, 256, 0, stream>>>(deg, N);
  count_deg_kernel<<<(E + 255) / 256, 256, 0, stream>>>(dst, deg, E);
  int nb = (N + SCAN_BLK - 1) / SCAN_BLK;  // 49 for N=50000; scan2 handles nb<=256
  scan1_kernel<<<nb, 256, 0, stream>>>(deg, bsum, N);
  scan2_kernel<<<1, 256, 0, stream>>>(bsum, nb);
  scan3_kernel<<<nb, 256, 0, stream>>>(deg, bsum, offs, cursor, inv_deg, N, E);
  scatter_kernel<<<(E + 255) / 256, 256, 0, stream>>>(src, dst, cursor, esrc, E);

  int mtiles = (N + BM - 1) / BM;
  const int pack_elems = 256 * 512 + 128 * 512 + 384;
  for (int l = 0; l < L; ++l) {
    const size_t lND = (size_t)l * N * D;
    const bf16* inpA = (l == 0) ? (const bf16*)x : ((const bf16*)d_out + lND - (size_t)N * D);
    const bf16* hlA = (const bf16*)h + lND;
    const bf16* hlB = hb + lND;

    pack_kernel<<<(pack_elems + 255) / 256, 256, 0, stream>>>(Wl, Wr, b, l, flag, B1p, B2p, bs1,
                                                              bs2);
    agg_dual_kernel<<<(N + 3) / 4, 256, 0, stream>>>(inpA, xb, hlA, hlB, flag, esrc, offs, inv_deg,
                                                     agg_inp, agg2, N);
    gemm1_kernel<<<dim3(mtiles, 2), 256, 0, stream>>>(agg_inp, inpA, xb, agg2, hlA, hlB, flag, B1p,
                                                      bs1, z, rh, N);
    agg_kernel<<<(N + 3) / 4, 256, 0, stream>>>(rh, rh, flag, esrc, offs, inv_deg, agg2, N);
    gemm2_kernel<<<dim3(mtiles, 1), 256, 0, stream>>>(agg_inp, inpA, xb, agg2, rh, hlA, hlB, flag,
                                                      B2p, bs2, z, d_out, lND, xb, N);
  }
}